// Round 1
// baseline (949.152 us; speedup 1.0000x reference)
//
#include <hip/hip_runtime.h>
#include <math.h>

#define BB 32
#define DD 128
#define TLEN 4096
#define NSEG 512
#define HOP 256
#define NFR 17
#define NBINS 257
#define STOT 4369
#define NPATCH 196
#define NFREQ 99
#define OLAL 4608

// workspace layout (float offsets)
#define FBT2_OFF 0
#define FBT2_SZ  (DD * NFR * NBINS * 2)       // 1,118,464
#define GBUF_OFF (FBT2_OFF + FBT2_SZ)
#define GATE_OFF (GBUF_OFF + BB * DD)
#define ZI_OFF   (GATE_OFF + BB * DD)
#define ZI_SZ    (BB * NFREQ * DD * 2)        // 811,008
#define X0I_OFF  (ZI_OFF + ZI_SZ)
#define X0I_SZ   (BB * NPATCH * DD)           // 802,816
#define XT_OFF   (X0I_OFF + X0I_SZ)           // 2,740,480; + 16,777,216 -> ~78 MB total

__device__ __forceinline__ float gelu_exact(float x) {
    return 0.5f * x * (1.0f + erff(x * 0.70710678118654752f));
}

// ---------------------------------------------------------------- zero gbuf
__global__ __launch_bounds__(256) void zero_kernel(float* p, int n) {
    int i = blockIdx.x * 256 + threadIdx.x;
    if (i < n) p[i] = 0.0f;
}

// ------------------------------------------------- tfb -> fbt2 (D,17,257,2)
// c coefficients: cos(fl(pi)) = cos(fl(3*pi)) = -1.0f exactly in fp32.
__global__ __launch_bounds__(256) void prep_fb(const float* __restrict__ tfb,
                                               float* __restrict__ fbt2) {
    int idx = blockIdx.x * 256 + threadIdx.x;
    if (idx >= STOT * DD) return;
    int d = idx & 127;
    int s = idx >> 7;
    float2 a = ((const float2*)tfb)[s * DD + d];
    float2 b = ((const float2*)tfb)[STOT * DD + s * DD + d];
    int f = s / NFR, t = s % NFR;
    float2 r;
    r.x = -(a.x + b.x);
    r.y = -(a.y + b.y);
    ((float2*)fbt2)[((size_t)d * NFR + t) * NBINS + f] = r;
}

// ------------------------------------------------- ecg (B,T,D) -> (B,D,T)
__global__ __launch_bounds__(256) void transpose_btd(const float* __restrict__ in,
                                                     float* __restrict__ out) {
    __shared__ float tile[32][33];
    int b = blockIdx.z;
    int t0 = blockIdx.x * 32;
    int d0 = blockIdx.y * 32;
    int lx = threadIdx.x;   // 0..31
    int ly = threadIdx.y;   // 0..7
    for (int i = ly; i < 32; i += 8)
        tile[i][lx] = in[((size_t)b * TLEN + t0 + i) * DD + d0 + lx];
    __syncthreads();
    for (int i = ly; i < 32; i += 8)
        out[((size_t)b * DD + d0 + i) * TLEN + t0 + lx] = tile[lx][i];
}

// ---------------------------------------- image rfft(ortho) + filter + g acc
// grid: (B*11) blocks, 128 threads (d). Each block does 9 freq bins.
__global__ __launch_bounds__(128) void img_dft(const float* __restrict__ image,
                                               const float* __restrict__ ifb,
                                               const float* __restrict__ sel,
                                               float* __restrict__ zi,
                                               float* __restrict__ gbuf) {
    __shared__ float ctab[NPATCH], stab[NPATCH];
    int b = blockIdx.x / 11;
    int fg = blockIdx.x % 11;
    int d = threadIdx.x;
    for (int m = d; m < NPATCH; m += 128) {
        ctab[m] = cospif(m * (2.0f / 196.0f));
        stab[m] = sinpif(m * (2.0f / 196.0f));
    }
    __syncthreads();
    float accr[9], acci[9];
    int mc[9];
#pragma unroll
    for (int j = 0; j < 9; ++j) { accr[j] = 0.0f; acci[j] = 0.0f; mc[j] = 0; }
    const float* img = image + (size_t)b * NPATCH * DD + d;
    for (int n = 0; n < NPATCH; ++n) {
        float v = img[(size_t)n * DD];
#pragma unroll
        for (int j = 0; j < 9; ++j) {
            float c = ctab[mc[j]], s = stab[mc[j]];
            accr[j] += v * c;
            acci[j] -= v * s;
            mc[j] += fg * 9 + j;                    // (f*n) mod 196, stepped
            if (mc[j] >= NPATCH) mc[j] -= NPATCH;
        }
    }
    float gg = 0.0f;
#pragma unroll
    for (int j = 0; j < 9; ++j) {
        int f = fg * 9 + j;
        float Xr = accr[j] * (1.0f / 14.0f);        // ortho: /sqrt(196)
        float Xi = acci[j] * (1.0f / 14.0f);
        float sr = (Xr * Xr - Xi * Xi) * (1.0f / 99.0f);
        float si = 2.0f * Xr * Xi * (1.0f / 99.0f);
        float2 f0 = ((const float2*)ifb)[f * DD + d];
        float2 f1 = ((const float2*)ifb)[NFREQ * DD + f * DD + d];
        float fbr = -(f0.x + f1.x), fbi = -(f0.y + f1.y);
        float zr = sr * fbr - si * fbi;
        float zm = sr * fbi + si * fbr;
        float2 o; o.x = zr; o.y = zm;
        ((float2*)zi)[((size_t)b * NFREQ + f) * DD + d] = o;
        float2 sl = ((const float2*)sel)[f * DD + d];
        gg += zr * sl.x - zm * sl.y;
    }
    atomicAdd(gbuf + b * DD + d, gg * (1.0f / 99.0f));
}

// ----------------------------------------------------- gate = g @ w^T + b
__global__ __launch_bounds__(128) void gate_kernel(const float* __restrict__ gbuf,
                                                   const float* __restrict__ w,
                                                   const float* __restrict__ bias,
                                                   float* __restrict__ gate) {
    __shared__ float gs[DD];
    int b = blockIdx.x, e = threadIdx.x;
    gs[e] = gbuf[b * DD + e];
    __syncthreads();
    float acc = bias[e];
    const float* wr = w + (size_t)e * DD;
    for (int d = 0; d < DD; ++d) acc += gs[d] * wr[d];
    gate[b * DD + e] = acc;
}

// ------------------------- per-(b,d): STFT -> filter*gate -> ISTFT, in-place
__global__ __launch_bounds__(256) void stft_filter_istft(float* xT,   // (B*D, 4096) in+out
                                                         const float* __restrict__ fbt2,
                                                         const float* __restrict__ gate) {
    __shared__ float xs[OLAL];
    __shared__ float ola[OLAL];
    __shared__ float ar[256], ai[256];
    __shared__ float yr[NBINS], yi[NBINS];
    __shared__ float twc[128], tws[128];
    __shared__ float win[NSEG];
    int tid = threadIdx.x;
    int bd = blockIdx.x;     // b*128 + d
    int d = bd & 127;
    float gat = gate[bd];
    for (int j = tid; j < NSEG; j += 256)
        win[j] = 0.5f - 0.5f * cospif(j * (1.0f / 256.0f));   // sin^2(pi j/512)
    for (int j = tid; j < 128; j += 256) {
        twc[j] = cospif(j * (1.0f / 128.0f));                 // e^{-2pi i j/256}
        tws[j] = -sinpif(j * (1.0f / 128.0f));
    }
    for (int j = tid; j < OLAL; j += 256) ola[j] = 0.0f;
    for (int j = tid; j < HOP; j += 256) { xs[j] = 0.0f; xs[OLAL - HOP + j] = 0.0f; }
    float* xrow = xT + (size_t)bd * TLEN;
    for (int j = tid; j < TLEN; j += 256) xs[HOP + j] = xrow[j];
    const float2* fbrow = (const float2*)(fbt2 + (size_t)d * NFR * NBINS * 2);
    const float scl = gat * (1.0f / 4369.0f);

    for (int t = 0; t < NFR; ++t) {
        __syncthreads();
        {   // pack even/odd + bit-reverse (512-real -> 256-complex)
            int m = tid;
            float e = xs[t * HOP + 2 * m] * win[2 * m];
            float o = xs[t * HOP + 2 * m + 1] * win[2 * m + 1];
            int r = __brev((unsigned)m) >> 24;
            ar[r] = e; ai[r] = o;
        }
        __syncthreads();
        // forward 256-pt DIT FFT
        for (int s = 1; s <= 8; ++s) {
            if (tid < 128) {
                int half = 1 << (s - 1);
                int k = tid & (half - 1);
                int p = ((tid >> (s - 1)) << s) + k;
                int twi = k << (8 - s);
                float c = twc[twi], sn = tws[twi];
                float ur = ar[p], ui = ai[p];
                float vr = ar[p + half], vi = ai[p + half];
                float tr = vr * c - vi * sn;
                float ti = vr * sn + vi * c;
                ar[p] = ur + tr; ai[p] = ui + ti;
                ar[p + half] = ur - tr; ai[p + half] = ui - ti;
            }
            __syncthreads();
        }
        {   // untangle to rfft bins, /WSUM, square, filter, gate
            int k = tid;
            float Xr, Xi;
            if (k == 0) {
                float re = ar[0], im = ai[0];
                Xr = re + im; Xi = 0.0f;
                float zr2 = (re - im) * (1.0f / 256.0f);      // Nyquist bin (real)
                float2 fb2 = fbrow[t * NBINS + 256];
                yr[256] = zr2 * zr2 * fb2.x * scl;
                yi[256] = 0.0f;                               // c2r drops Nyquist imag
            } else {
                float Ar = ar[k], Ai = ai[k];
                float Br = ar[256 - k], Bi = -ai[256 - k];
                float xer = 0.5f * (Ar + Br), xei = 0.5f * (Ai + Bi);
                float xor_ = 0.5f * (Ai - Bi), xoi = -0.5f * (Ar - Br);
                float c = cospif(k * (1.0f / 256.0f));
                float sn = sinpif(k * (1.0f / 256.0f));       // W = c - i*sn
                Xr = xer + c * xor_ + sn * xoi;
                Xi = xei + c * xoi - sn * xor_;
            }
            float zr = Xr * (1.0f / 256.0f), zi2 = Xi * (1.0f / 256.0f);
            float sr = zr * zr - zi2 * zi2;
            float si = 2.0f * zr * zi2;
            float2 fb = fbrow[t * NBINS + k];
            float Yr = (sr * fb.x - si * fb.y) * scl;
            float Yi = (sr * fb.y + si * fb.x) * scl;
            if (k == 0) Yi = 0.0f;                            // c2r drops DC imag
            yr[k] = Yr; yi[k] = Yi;
        }
        __syncthreads();
        {   // build conj(Zinv) bit-reversed for inverse-via-forward FFT
            int m = tid;
            float Ymr = yr[m], Ymi = yi[m];
            float Ycr = yr[256 - m], Yci = -yi[256 - m];
            float Er = 0.5f * (Ymr + Ycr), Ei = 0.5f * (Ymi + Yci);
            float Dr = 0.5f * (Ymr - Ycr), Di = 0.5f * (Ymi - Yci);
            float c = cospif(m * (1.0f / 256.0f));
            float sn = sinpif(m * (1.0f / 256.0f));           // e^{+2pi i m/512}
            float Or = Dr * c - Di * sn;
            float Oi = Dr * sn + Di * c;
            int r = __brev((unsigned)m) >> 24;
            ar[r] = Er - Oi;
            ai[r] = -(Ei + Or);
        }
        __syncthreads();
        // inverse FFT = conj(forward(conj)) / 256  (the /256 cancels *WSUM)
        for (int s = 1; s <= 8; ++s) {
            if (tid < 128) {
                int half = 1 << (s - 1);
                int k = tid & (half - 1);
                int p = ((tid >> (s - 1)) << s) + k;
                int twi = k << (8 - s);
                float c = twc[twi], sn = tws[twi];
                float ur = ar[p], ui = ai[p];
                float vr = ar[p + half], vi = ai[p + half];
                float tr = vr * c - vi * sn;
                float ti = vr * sn + vi * c;
                ar[p] = ur + tr; ai[p] = ui + ti;
                ar[p + half] = ur - tr; ai[p + half] = ui - ti;
            }
            __syncthreads();
        }
        {   // unpack + synthesis window + OLA  (y*WSUM*win; /256*256 cancels)
            int m = tid;
            ola[t * HOP + 2 * m]     += ar[m] * win[2 * m];
            ola[t * HOP + 2 * m + 1] += -ai[m] * win[2 * m + 1];
        }
    }
    __syncthreads();
    // divide by OLA norm (always exactly 2 overlapping frames in [256,4352))
    for (int j = tid; j < TLEN; j += 256) {
        int p = j + HOP;
        float s2 = win[p & 255];          // sin^2
        float c2 = 1.0f - s2;             // cos^2
        xrow[j] = ola[p] / (s2 * s2 + c2 * c2);
    }
}

// ------------------------------------------- image irfft(ortho) + add image
// grid: (B*14) blocks, 128 threads (d). Each block does 14 time positions.
__global__ __launch_bounds__(128) void img_irfft(const float* __restrict__ zi,
                                                 const float* __restrict__ image,
                                                 float* __restrict__ x0img) {
    __shared__ float ctab[NPATCH], stab[NPATCH];
    int b = blockIdx.x / 14;
    int ng = blockIdx.x % 14;
    int d = threadIdx.x;
    for (int m = d; m < NPATCH; m += 128) {
        ctab[m] = cospif(m * (2.0f / 196.0f));
        stab[m] = sinpif(m * (2.0f / 196.0f));
    }
    __syncthreads();
    const float2* zrow = (const float2*)zi + (size_t)b * NFREQ * DD + d;
    float acc[14];
    int mc[14];
    float2 z0 = zrow[0];
#pragma unroll
    for (int j = 0; j < 14; ++j) { acc[j] = z0.x; mc[j] = 0; }  // Re(DC) only
    for (int f = 1; f <= 97; ++f) {
        float2 z = zrow[(size_t)f * DD];
#pragma unroll
        for (int j = 0; j < 14; ++j) {
            int n = ng * 14 + j;
            mc[j] += n;                                 // (f*n) mod 196
            if (mc[j] >= NPATCH) mc[j] -= NPATCH;
            acc[j] += 2.0f * (z.x * ctab[mc[j]] - z.y * stab[mc[j]]);
        }
    }
    float2 z98 = zrow[98 * (size_t)DD];
#pragma unroll
    for (int j = 0; j < 14; ++j) {
        int n = ng * 14 + j;
        float a = acc[j] + ((n & 1) ? -z98.x : z98.x);  // Re(Nyquist) only
        float y = a * (1.0f / 14.0f);                   // ortho inverse scale
        size_t idx = ((size_t)b * NPATCH + n) * DD + d;
        x0img[idx] = y + image[idx];
    }
}

// ------------------------------- addnorm: LN1 -> gelu MLP (fp32) -> LN2
// FUSED=1: x0 = ecgT(b,d,t) transposed-read + ecg(b,t,d); grid = B*(T/64)
// FUSED=0: x0 = plain rows buffer; grid = rows/64
template <int FUSED>
__global__ __launch_bounds__(256) void addnorm_kernel(
    const float* __restrict__ srcA, const float* __restrict__ srcB,
    const float* __restrict__ ln1g, const float* __restrict__ ln1b,
    const float* __restrict__ w1, const float* __restrict__ b1,
    const float* __restrict__ w2, const float* __restrict__ b2,
    const float* __restrict__ ln2g, const float* __restrict__ ln2b,
    float* __restrict__ out) {
    __shared__ float xln[64 * 129];   // reused: x -> g -> h
    int tid = threadIdx.x;
    int b = 0, t0 = 0;
    size_t R0 = 0;
    // ---- Phase A: build x0
    if (FUSED) {
        b = blockIdx.x >> 6;
        t0 = (blockIdx.x & 63) * 64;
        for (int i = tid; i < 64 * 128; i += 256) {
            int dd = i >> 6, r = i & 63;
            xln[r * 129 + dd] = srcA[((size_t)b * DD + dd) * TLEN + t0 + r];
        }
        __syncthreads();
        for (int i = tid; i < 64 * 128; i += 256) {
            int r = i >> 7, dd = i & 127;
            xln[r * 129 + dd] += srcB[((size_t)b * TLEN + t0 + r) * DD + dd];
        }
    } else {
        R0 = (size_t)blockIdx.x * 64;
        for (int i = tid; i < 64 * 128; i += 256) {
            int r = i >> 7, dd = i & 127;
            xln[r * 129 + dd] = srcA[(R0 + r) * DD + dd];
        }
    }
    __syncthreads();
    // ---- LN1 (wave per row)
    int wave = tid >> 6, lane = tid & 63;
    for (int r = wave; r < 64; r += 4) {
        float v0 = xln[r * 129 + lane];
        float v1 = xln[r * 129 + 64 + lane];
        float s = v0 + v1, ss = v0 * v0 + v1 * v1;
        for (int off = 32; off > 0; off >>= 1) {
            s += __shfl_xor(s, off);
            ss += __shfl_xor(ss, off);
        }
        float mean = s * (1.0f / 128.0f);
        float var = ss * (1.0f / 128.0f) - mean * mean;
        float rstd = rsqrtf(var + 1e-5f);
        xln[r * 129 + lane] = (v0 - mean) * rstd * ln1g[lane] + ln1b[lane];
        xln[r * 129 + 64 + lane] = (v1 - mean) * rstd * ln1g[64 + lane] + ln1b[64 + lane];
    }
    __syncthreads();
    // ---- thread tiling: 8 rows x 4 cols each
    int ec = tid & 31, rg = tid >> 5;
    float res[8][4];
#pragma unroll
    for (int rr = 0; rr < 8; ++rr)
#pragma unroll
        for (int j = 0; j < 4; ++j)
            res[rr][j] = xln[(rg * 8 + rr) * 129 + 4 * ec + j];   // residual (post-LN1)
    // ---- Phase B: g = gelu(x @ w1 + b1)
    float acc[8][4];
#pragma unroll
    for (int rr = 0; rr < 8; ++rr)
#pragma unroll
        for (int j = 0; j < 4; ++j) acc[rr][j] = 0.0f;
    {
        const float4* w1v = (const float4*)w1;
        for (int k = 0; k < 128; ++k) {
            float4 wv = w1v[k * 32 + ec];
#pragma unroll
            for (int rr = 0; rr < 8; ++rr) {
                float xv = xln[(rg * 8 + rr) * 129 + k];
                acc[rr][0] += xv * wv.x; acc[rr][1] += xv * wv.y;
                acc[rr][2] += xv * wv.z; acc[rr][3] += xv * wv.w;
            }
        }
    }
    float4 b1v = ((const float4*)b1)[ec];
#pragma unroll
    for (int rr = 0; rr < 8; ++rr) {
        acc[rr][0] = gelu_exact(acc[rr][0] + b1v.x);
        acc[rr][1] = gelu_exact(acc[rr][1] + b1v.y);
        acc[rr][2] = gelu_exact(acc[rr][2] + b1v.z);
        acc[rr][3] = gelu_exact(acc[rr][3] + b1v.w);
    }
    __syncthreads();   // all reads of xln(=x) done
#pragma unroll
    for (int rr = 0; rr < 8; ++rr)
#pragma unroll
        for (int j = 0; j < 4; ++j)
            xln[(rg * 8 + rr) * 129 + 4 * ec + j] = acc[rr][j];   // xln := g
    __syncthreads();
    // ---- Phase C: h = g @ w2 + b2 + res
#pragma unroll
    for (int rr = 0; rr < 8; ++rr)
#pragma unroll
        for (int j = 0; j < 4; ++j) acc[rr][j] = 0.0f;
    {
        const float4* w2v = (const float4*)w2;
        for (int k = 0; k < 128; ++k) {
            float4 wv = w2v[k * 32 + ec];
#pragma unroll
            for (int rr = 0; rr < 8; ++rr) {
                float gv = xln[(rg * 8 + rr) * 129 + k];
                acc[rr][0] += gv * wv.x; acc[rr][1] += gv * wv.y;
                acc[rr][2] += gv * wv.z; acc[rr][3] += gv * wv.w;
            }
        }
    }
    float4 b2v = ((const float4*)b2)[ec];
#pragma unroll
    for (int rr = 0; rr < 8; ++rr) {
        acc[rr][0] += b2v.x + res[rr][0];
        acc[rr][1] += b2v.y + res[rr][1];
        acc[rr][2] += b2v.z + res[rr][2];
        acc[rr][3] += b2v.w + res[rr][3];
    }
    __syncthreads();   // all reads of xln(=g) done
#pragma unroll
    for (int rr = 0; rr < 8; ++rr)
#pragma unroll
        for (int j = 0; j < 4; ++j)
            xln[(rg * 8 + rr) * 129 + 4 * ec + j] = acc[rr][j];   // xln := h
    __syncthreads();
    // ---- LN2 + store
    for (int r = wave; r < 64; r += 4) {
        float v0 = xln[r * 129 + lane];
        float v1 = xln[r * 129 + 64 + lane];
        float s = v0 + v1, ss = v0 * v0 + v1 * v1;
        for (int off = 32; off > 0; off >>= 1) {
            s += __shfl_xor(s, off);
            ss += __shfl_xor(ss, off);
        }
        float mean = s * (1.0f / 128.0f);
        float var = ss * (1.0f / 128.0f) - mean * mean;
        float rstd = rsqrtf(var + 1e-5f);
        size_t orow = FUSED ? ((size_t)b * TLEN + t0 + r) * DD : (R0 + r) * DD;
        out[orow + lane] = (v0 - mean) * rstd * ln2g[lane] + ln2b[lane];
        out[orow + 64 + lane] = (v1 - mean) * rstd * ln2g[64 + lane] + ln2b[64 + lane];
    }
}

extern "C" void kernel_launch(void* const* d_in, const int* in_sizes, int n_in,
                              void* d_out, int out_size, void* d_ws, size_t ws_size,
                              hipStream_t stream) {
    (void)in_sizes; (void)n_in; (void)out_size; (void)ws_size;
    const float* ecg   = (const float*)d_in[0];
    const float* image = (const float*)d_in[1];
    const float* tfb   = (const float*)d_in[2];
    const float* ifb   = (const float*)d_in[3];
    const float* sel   = (const float*)d_in[4];
    const float* i2t_w = (const float*)d_in[5];
    const float* i2t_b = (const float*)d_in[6];
    const float* t_ln1_g = (const float*)d_in[7];
    const float* t_ln1_b = (const float*)d_in[8];
    const float* t_w1 = (const float*)d_in[9];
    const float* t_b1 = (const float*)d_in[10];
    const float* t_w2 = (const float*)d_in[11];
    const float* t_b2 = (const float*)d_in[12];
    const float* t_ln2_g = (const float*)d_in[13];
    const float* t_ln2_b = (const float*)d_in[14];
    const float* i_ln1_g = (const float*)d_in[15];
    const float* i_ln1_b = (const float*)d_in[16];
    const float* i_w1 = (const float*)d_in[17];
    const float* i_b1 = (const float*)d_in[18];
    const float* i_w2 = (const float*)d_in[19];
    const float* i_b2 = (const float*)d_in[20];
    const float* i_ln2_g = (const float*)d_in[21];
    const float* i_ln2_b = (const float*)d_in[22];
    float* out = (float*)d_out;
    float* ws = (float*)d_ws;

    // ws is re-poisoned each call: zero the atomic accumulator
    zero_kernel<<<16, 256, 0, stream>>>(ws + GBUF_OFF, BB * DD);
    prep_fb<<<(STOT * DD + 255) / 256, 256, 0, stream>>>(tfb, ws + FBT2_OFF);
    {
        dim3 tb(32, 8);
        dim3 tg(TLEN / 32, DD / 32, BB);
        transpose_btd<<<tg, tb, 0, stream>>>(ecg, ws + XT_OFF);
    }
    img_dft<<<BB * 11, 128, 0, stream>>>(image, ifb, sel, ws + ZI_OFF, ws + GBUF_OFF);
    gate_kernel<<<BB, 128, 0, stream>>>(ws + GBUF_OFF, i2t_w, i2t_b, ws + GATE_OFF);
    stft_filter_istft<<<BB * DD, 256, 0, stream>>>(ws + XT_OFF, ws + FBT2_OFF, ws + GATE_OFF);
    addnorm_kernel<1><<<BB * (TLEN / 64), 256, 0, stream>>>(
        ws + XT_OFF, ecg, t_ln1_g, t_ln1_b, t_w1, t_b1, t_w2, t_b2, t_ln2_g, t_ln2_b, out);
    img_irfft<<<BB * 14, 128, 0, stream>>>(ws + ZI_OFF, image, ws + X0I_OFF);
    addnorm_kernel<0><<<(BB * NPATCH) / 64, 256, 0, stream>>>(
        ws + X0I_OFF, nullptr, i_ln1_g, i_ln1_b, i_w1, i_b1, i_w2, i_b2, i_ln2_g, i_ln2_b,
        out + (size_t)BB * TLEN * DD);
}

// Round 2
// 800.200 us; speedup vs baseline: 1.1861x; 1.1861x over previous
//
#include <hip/hip_runtime.h>
#include <math.h>

#define BB 32
#define DD 128
#define TLEN 4096
#define NSEG 512
#define HOP 256
#define NFR 17
#define NBINS 257
#define STOT 4369
#define NPATCH 196
#define NFREQ 99
#define OLAL 4608

// workspace layout (float offsets)
#define FBT2_OFF 0
#define FBT2_SZ  (DD * NFR * NBINS * 2)       // 1,118,464
#define GBUF_OFF (FBT2_OFF + FBT2_SZ)
#define GATE_OFF (GBUF_OFF + BB * DD)
#define ZI_OFF   (GATE_OFF + BB * DD)
#define ZI_SZ    (BB * NFREQ * DD * 2)        // 811,008
#define X0I_OFF  (ZI_OFF + ZI_SZ)
#define X0I_SZ   (BB * NPATCH * DD)           // 802,816
#define XT_OFF   (X0I_OFF + X0I_SZ)

__device__ __forceinline__ float gelu_exact(float x) {
    return 0.5f * x * (1.0f + erff(x * 0.70710678118654752f));
}

// ---------------------------------------------------------------- zero gbuf
__global__ __launch_bounds__(256) void zero_kernel(float* p, int n) {
    int i = blockIdx.x * 256 + threadIdx.x;
    if (i < n) p[i] = 0.0f;
}

// ------------------------------------------------- tfb -> fbt2 (D,17,257,2)
// c coefficients: cos(fl(pi)) = cos(fl(3*pi)) = -1.0f exactly in fp32.
__global__ __launch_bounds__(256) void prep_fb(const float* __restrict__ tfb,
                                               float* __restrict__ fbt2) {
    int idx = blockIdx.x * 256 + threadIdx.x;
    if (idx >= STOT * DD) return;
    int d = idx & 127;
    int s = idx >> 7;
    float2 a = ((const float2*)tfb)[s * DD + d];
    float2 b = ((const float2*)tfb)[STOT * DD + s * DD + d];
    int f = s / NFR, t = s % NFR;
    float2 r;
    r.x = -(a.x + b.x);
    r.y = -(a.y + b.y);
    ((float2*)fbt2)[((size_t)d * NFR + t) * NBINS + f] = r;
}

// ------------------------------------------------- ecg (B,T,D) -> (B,D,T)
__global__ __launch_bounds__(256) void transpose_btd(const float* __restrict__ in,
                                                     float* __restrict__ out) {
    __shared__ float tile[32][33];
    int b = blockIdx.z;
    int t0 = blockIdx.x * 32;
    int d0 = blockIdx.y * 32;
    int lx = threadIdx.x;   // 0..31
    int ly = threadIdx.y;   // 0..7
    for (int i = ly; i < 32; i += 8)
        tile[i][lx] = in[((size_t)b * TLEN + t0 + i) * DD + d0 + lx];
    __syncthreads();
    for (int i = ly; i < 32; i += 8)
        out[((size_t)b * DD + d0 + i) * TLEN + t0 + lx] = tile[lx][i];
}

// ---------------------------------------- image rfft(ortho) + filter + g acc
__global__ __launch_bounds__(128) void img_dft(const float* __restrict__ image,
                                               const float* __restrict__ ifb,
                                               const float* __restrict__ sel,
                                               float* __restrict__ zi,
                                               float* __restrict__ gbuf) {
    __shared__ float ctab[NPATCH], stab[NPATCH];
    int b = blockIdx.x / 11;
    int fg = blockIdx.x % 11;
    int d = threadIdx.x;
    for (int m = d; m < NPATCH; m += 128) {
        ctab[m] = cospif(m * (2.0f / 196.0f));
        stab[m] = sinpif(m * (2.0f / 196.0f));
    }
    __syncthreads();
    float accr[9], acci[9];
    int mc[9];
#pragma unroll
    for (int j = 0; j < 9; ++j) { accr[j] = 0.0f; acci[j] = 0.0f; mc[j] = 0; }
    const float* img = image + (size_t)b * NPATCH * DD + d;
    for (int n = 0; n < NPATCH; ++n) {
        float v = img[(size_t)n * DD];
#pragma unroll
        for (int j = 0; j < 9; ++j) {
            float c = ctab[mc[j]], s = stab[mc[j]];
            accr[j] += v * c;
            acci[j] -= v * s;
            mc[j] += fg * 9 + j;
            if (mc[j] >= NPATCH) mc[j] -= NPATCH;
        }
    }
    float gg = 0.0f;
#pragma unroll
    for (int j = 0; j < 9; ++j) {
        int f = fg * 9 + j;
        float Xr = accr[j] * (1.0f / 14.0f);
        float Xi = acci[j] * (1.0f / 14.0f);
        float sr = (Xr * Xr - Xi * Xi) * (1.0f / 99.0f);
        float si = 2.0f * Xr * Xi * (1.0f / 99.0f);
        float2 f0 = ((const float2*)ifb)[f * DD + d];
        float2 f1 = ((const float2*)ifb)[NFREQ * DD + f * DD + d];
        float fbr = -(f0.x + f1.x), fbi = -(f0.y + f1.y);
        float zr = sr * fbr - si * fbi;
        float zm = sr * fbi + si * fbr;
        float2 o; o.x = zr; o.y = zm;
        ((float2*)zi)[((size_t)b * NFREQ + f) * DD + d] = o;
        float2 sl = ((const float2*)sel)[f * DD + d];
        gg += zr * sl.x - zm * sl.y;
    }
    atomicAdd(gbuf + b * DD + d, gg * (1.0f / 99.0f));
}

// ----------------------------------------------------- gate = g @ w^T + b
__global__ __launch_bounds__(128) void gate_kernel(const float* __restrict__ gbuf,
                                                   const float* __restrict__ w,
                                                   const float* __restrict__ bias,
                                                   float* __restrict__ gate) {
    __shared__ float gs[DD];
    int b = blockIdx.x, e = threadIdx.x;
    gs[e] = gbuf[b * DD + e];
    __syncthreads();
    float acc = bias[e];
    const float* wr = w + (size_t)e * DD;
    for (int d = 0; d < DD; ++d) acc += gs[d] * wr[d];
    gate[b * DD + e] = acc;
}

// ------------------------- per-(b,d): STFT -> filter*gate -> ISTFT, in-place
// All 17 frames processed concurrently: 20 barriers/block (was ~340), 8.5
// butterflies/thread/stage. LDS addresses skewed (i + i/32) so the small-
// stride FFT stages and bit-reverse writes are <=2-way (free) instead of
// 4-way/8-way. 39.0 KB LDS -> 4 blocks/CU.
#define SKN 264   // skewed per-frame stride = SK(256)
#define SK(i) ((i) + ((i) >> 5))

__global__ __launch_bounds__(256, 4) void stft_filter_istft(
    float* xT, const float* __restrict__ fbt2, const float* __restrict__ gate) {
    __shared__ float ar[NFR * SKN];   // 4488
    __shared__ float ai[NFR * SKN];
    __shared__ float win[NSEG];
    __shared__ float twc[128], tws[128];
    int tid = threadIdx.x;
    int bd = blockIdx.x;              // b*128 + d
    int d = bd & 127;
    float gat = gate[bd];
    const float scl = gat * (1.0f / 4369.0f);
    float* xrow = xT + (size_t)bd * TLEN;
    const float2* fbrow = (const float2*)(fbt2 + (size_t)d * NFR * NBINS * 2);

    for (int j = tid; j < NSEG; j += 256)
        win[j] = 0.5f - 0.5f * cospif(j * (1.0f / 256.0f));   // sin^2(pi j/512)
    if (tid < 128) {
        twc[tid] = cospif(tid * (1.0f / 128.0f));             // e^{-2pi i j/256}
        tws[tid] = -sinpif(tid * (1.0f / 128.0f));
    }
    __syncthreads();

    // ---- pack all frames: even/odd real pairs -> bit-reversed complex
    // frame t sample n: xp[t*256+n], xp = [256 zeros | x | 256 zeros]
    for (int t = 0; t < NFR; ++t) {
        int m = tid;                       // 0..255
        int src = t * HOP + 2 * m - HOP;   // index of even sample in x
        float e = 0.0f, o = 0.0f;
        if (src >= 0 && src < TLEN) {
            float2 v = *(const float2*)(xrow + src);
            e = v.x; o = v.y;
        }
        e *= win[2 * m]; o *= win[2 * m + 1];
        int r = __brev((unsigned)m) >> 24;
        ar[t * SKN + SK(r)] = e;
        ai[t * SKN + SK(r)] = o;
    }

    // ---- forward 256-pt DIT FFT, all 17 frames per stage
    for (int s = 1; s <= 8; ++s) {
        __syncthreads();
        int half = 1 << (s - 1);
        for (int j = tid; j < NFR * 128; j += 256) {
            int t = j >> 7, m = j & 127;
            int base = t * SKN;
            int k = m & (half - 1);
            int p = ((m >> (s - 1)) << s) + k;
            int twi = k << (8 - s);
            float c = twc[twi], sn = tws[twi];
            int a0 = base + SK(p), a1 = base + SK(p + half);
            float ur = ar[a0], ui = ai[a0];
            float vr = ar[a1], vi = ai[a1];
            float tr = vr * c - vi * sn;
            float ti = vr * sn + vi * c;
            ar[a0] = ur + tr; ai[a0] = ui + ti;
            ar[a1] = ur - tr; ai[a1] = ui - ti;
        }
    }
    __syncthreads();

    // ---- phase 1: untangle rfft bins (m, 256-m), /WSUM, square, filter
    // Y values held in registers across the barrier (in-place repack would
    // race with other threads' Z reads).
    float y1r[9], y1i[9], y2r[9], y2i[9];
#pragma unroll
    for (int it = 0; it < 9; ++it) {
        int j = tid + it * 256;
        if (j < NFR * 129) {
            int t = j / 129, m = j - t * 129;
            int base = t * SKN;
            const float2* fbr = fbrow + t * NBINS;
            if (m == 0) {
                float re = ar[base + SK(0)], im = ai[base + SK(0)];
                float z0 = (re + im) * (1.0f / 256.0f);   // DC (real)
                float zN = (re - im) * (1.0f / 256.0f);   // Nyquist (real)
                float2 fb0 = fbr[0], fbN = fbr[256];
                y1r[it] = z0 * z0 * fb0.x * scl; y1i[it] = 0.0f;  // c2r drops imag
                y2r[it] = zN * zN * fbN.x * scl; y2i[it] = 0.0f;
            } else if (m == 128) {
                float Zr = ar[base + SK(128)], Zi = ai[base + SK(128)];
                float zr = Zr * (1.0f / 256.0f), zi2 = -Zi * (1.0f / 256.0f);
                float sr = zr * zr - zi2 * zi2, si = 2.0f * zr * zi2;
                float2 fb = fbr[128];
                y1r[it] = (sr * fb.x - si * fb.y) * scl;
                y1i[it] = (sr * fb.y + si * fb.x) * scl;
                y2r[it] = 0.0f; y2i[it] = 0.0f;
            } else {
                float Amr = ar[base + SK(m)],       Ami = ai[base + SK(m)];
                float Acr = ar[base + SK(256 - m)], Aci = ai[base + SK(256 - m)];
                float c = cospif(m * (1.0f / 256.0f));
                float sn = sinpif(m * (1.0f / 256.0f));
                {   // bin m: A=Z[m], B=conj(Z[256-m])
                    float Br = Acr, Bi = -Aci;
                    float xer = 0.5f * (Amr + Br), xei = 0.5f * (Ami + Bi);
                    float xo_r = 0.5f * (Ami - Bi), xo_i = -0.5f * (Amr - Br);
                    float Xr = xer + c * xo_r + sn * xo_i;
                    float Xi = xei + c * xo_i - sn * xo_r;
                    float zr = Xr * (1.0f / 256.0f), zi2 = Xi * (1.0f / 256.0f);
                    float sr = zr * zr - zi2 * zi2, si = 2.0f * zr * zi2;
                    float2 fb = fbr[m];
                    y1r[it] = (sr * fb.x - si * fb.y) * scl;
                    y1i[it] = (sr * fb.y + si * fb.x) * scl;
                }
                {   // bin 256-m: A=Z[256-m], B=conj(Z[m]); cos->-c, sin->sn
                    float Br = Amr, Bi = -Ami;
                    float xer = 0.5f * (Acr + Br), xei = 0.5f * (Aci + Bi);
                    float xo_r = 0.5f * (Aci - Bi), xo_i = -0.5f * (Acr - Br);
                    float Xr = xer - c * xo_r + sn * xo_i;
                    float Xi = xei - c * xo_i - sn * xo_r;
                    float zr = Xr * (1.0f / 256.0f), zi2 = Xi * (1.0f / 256.0f);
                    float sr = zr * zr - zi2 * zi2, si = 2.0f * zr * zi2;
                    float2 fb = fbr[256 - m];
                    y2r[it] = (sr * fb.x - si * fb.y) * scl;
                    y2i[it] = (sr * fb.y + si * fb.x) * scl;
                }
            }
        }
    }
    __syncthreads();

    // ---- phase 2: conj-pack for inverse-via-forward FFT, bit-reversed write
#pragma unroll
    for (int it = 0; it < 9; ++it) {
        int j = tid + it * 256;
        if (j < NFR * 129) {
            int t = j / 129, m = j - t * 129;
            int base = t * SKN;
            if (m == 0) {
                float Er = 0.5f * (y1r[it] + y2r[it]);
                float Dr = 0.5f * (y1r[it] - y2r[it]);
                ar[base + SK(0)] = Er;      // c=1,sn=0: Er-Oi, Oi=0
                ai[base + SK(0)] = -Dr;     // -(Ei+Or) = -Dr
            } else if (m == 128) {
                ar[base + SK(1)] = y1r[it]; // brev(128)=1; c=0,sn=1
                ai[base + SK(1)] = y1i[it];
            } else {
                float c = cospif(m * (1.0f / 256.0f));
                float sn = sinpif(m * (1.0f / 256.0f));
                float Er = 0.5f * (y1r[it] + y2r[it]);
                float Ei = 0.5f * (y1i[it] - y2i[it]);
                float Dr = 0.5f * (y1r[it] - y2r[it]);
                float Di = 0.5f * (y1i[it] + y2i[it]);
                float Or = Dr * c - Di * sn;
                float Oi = Dr * sn + Di * c;
                int r1 = __brev((unsigned)m) >> 24;
                ar[base + SK(r1)] = Er - Oi;
                ai[base + SK(r1)] = -(Ei + Or);
                // position 256-m simplifies to (Er+Oi, Ei-Or)
                int r2 = __brev((unsigned)(256 - m)) >> 24;
                ar[base + SK(r2)] = Er + Oi;
                ai[base + SK(r2)] = Ei - Or;
            }
        }
    }

    // ---- inverse FFT (conj trick; /256 cancels *WSUM), all frames per stage
    for (int s = 1; s <= 8; ++s) {
        __syncthreads();
        int half = 1 << (s - 1);
        for (int j = tid; j < NFR * 128; j += 256) {
            int t = j >> 7, m = j & 127;
            int base = t * SKN;
            int k = m & (half - 1);
            int p = ((m >> (s - 1)) << s) + k;
            int twi = k << (8 - s);
            float c = twc[twi], sn = tws[twi];
            int a0 = base + SK(p), a1 = base + SK(p + half);
            float ur = ar[a0], ui = ai[a0];
            float vr = ar[a1], vi = ai[a1];
            float tr = vr * c - vi * sn;
            float ti = vr * sn + vi * c;
            ar[a0] = ur + tr; ai[a0] = ui + ti;
            ar[a1] = ur - tr; ai[a1] = ui - ti;
        }
    }
    __syncthreads();

    // ---- OLA directly from per-frame arrays (interior always 2 frames):
    // frame t sample n: even n -> ar[n/2], odd n -> -ai[n/2]; *win[n]
    for (int j = tid; j < TLEN; j += 256) {
        int p = j + HOP;
        int t1 = p >> 8;              // 1..16
        int t0 = t1 - 1;
        int i1 = p & 255;             // index in frame t1
        int i0 = i1 + 256;            // index in frame t0
        int h1 = t1 * SKN + SK(i1 >> 1);
        int h0 = t0 * SKN + SK(i0 >> 1);
        float v1, v0;
        if (j & 1) { v1 = -ai[h1]; v0 = -ai[h0]; }
        else       { v1 =  ar[h1]; v0 =  ar[h0]; }
        float s = v0 * win[i0] + v1 * win[i1];
        float s2 = win[i1];           // sin^2
        float c2 = 1.0f - s2;
        xrow[j] = s / (s2 * s2 + c2 * c2);
    }
}

// ------------------------------------------- image irfft(ortho) + add image
__global__ __launch_bounds__(128) void img_irfft(const float* __restrict__ zi,
                                                 const float* __restrict__ image,
                                                 float* __restrict__ x0img) {
    __shared__ float ctab[NPATCH], stab[NPATCH];
    int b = blockIdx.x / 14;
    int ng = blockIdx.x % 14;
    int d = threadIdx.x;
    for (int m = d; m < NPATCH; m += 128) {
        ctab[m] = cospif(m * (2.0f / 196.0f));
        stab[m] = sinpif(m * (2.0f / 196.0f));
    }
    __syncthreads();
    const float2* zrow = (const float2*)zi + (size_t)b * NFREQ * DD + d;
    float acc[14];
    int mc[14];
    float2 z0 = zrow[0];
#pragma unroll
    for (int j = 0; j < 14; ++j) { acc[j] = z0.x; mc[j] = 0; }
    for (int f = 1; f <= 97; ++f) {
        float2 z = zrow[(size_t)f * DD];
#pragma unroll
        for (int j = 0; j < 14; ++j) {
            int n = ng * 14 + j;
            mc[j] += n;
            if (mc[j] >= NPATCH) mc[j] -= NPATCH;
            acc[j] += 2.0f * (z.x * ctab[mc[j]] - z.y * stab[mc[j]]);
        }
    }
    float2 z98 = zrow[98 * (size_t)DD];
#pragma unroll
    for (int j = 0; j < 14; ++j) {
        int n = ng * 14 + j;
        float a = acc[j] + ((n & 1) ? -z98.x : z98.x);
        float y = a * (1.0f / 14.0f);
        size_t idx = ((size_t)b * NPATCH + n) * DD + d;
        x0img[idx] = y + image[idx];
    }
}

// ------------------------------- addnorm: LN1 -> gelu MLP (fp32) -> LN2
template <int FUSED>
__global__ __launch_bounds__(256) void addnorm_kernel(
    const float* __restrict__ srcA, const float* __restrict__ srcB,
    const float* __restrict__ ln1g, const float* __restrict__ ln1b,
    const float* __restrict__ w1, const float* __restrict__ b1,
    const float* __restrict__ w2, const float* __restrict__ b2,
    const float* __restrict__ ln2g, const float* __restrict__ ln2b,
    float* __restrict__ out) {
    __shared__ float xln[64 * 129];   // reused: x -> g -> h
    int tid = threadIdx.x;
    int b = 0, t0 = 0;
    size_t R0 = 0;
    if (FUSED) {
        b = blockIdx.x >> 6;
        t0 = (blockIdx.x & 63) * 64;
        for (int i = tid; i < 64 * 128; i += 256) {
            int dd = i >> 6, r = i & 63;
            xln[r * 129 + dd] = srcA[((size_t)b * DD + dd) * TLEN + t0 + r];
        }
        __syncthreads();
        for (int i = tid; i < 64 * 128; i += 256) {
            int r = i >> 7, dd = i & 127;
            xln[r * 129 + dd] += srcB[((size_t)b * TLEN + t0 + r) * DD + dd];
        }
    } else {
        R0 = (size_t)blockIdx.x * 64;
        for (int i = tid; i < 64 * 128; i += 256) {
            int r = i >> 7, dd = i & 127;
            xln[r * 129 + dd] = srcA[(R0 + r) * DD + dd];
        }
    }
    __syncthreads();
    int wave = tid >> 6, lane = tid & 63;
    for (int r = wave; r < 64; r += 4) {
        float v0 = xln[r * 129 + lane];
        float v1 = xln[r * 129 + 64 + lane];
        float s = v0 + v1, ss = v0 * v0 + v1 * v1;
        for (int off = 32; off > 0; off >>= 1) {
            s += __shfl_xor(s, off);
            ss += __shfl_xor(ss, off);
        }
        float mean = s * (1.0f / 128.0f);
        float var = ss * (1.0f / 128.0f) - mean * mean;
        float rstd = rsqrtf(var + 1e-5f);
        xln[r * 129 + lane] = (v0 - mean) * rstd * ln1g[lane] + ln1b[lane];
        xln[r * 129 + 64 + lane] = (v1 - mean) * rstd * ln1g[64 + lane] + ln1b[64 + lane];
    }
    __syncthreads();
    int ec = tid & 31, rg = tid >> 5;
    float res[8][4];
#pragma unroll
    for (int rr = 0; rr < 8; ++rr)
#pragma unroll
        for (int j = 0; j < 4; ++j)
            res[rr][j] = xln[(rg * 8 + rr) * 129 + 4 * ec + j];
    float acc[8][4];
#pragma unroll
    for (int rr = 0; rr < 8; ++rr)
#pragma unroll
        for (int j = 0; j < 4; ++j) acc[rr][j] = 0.0f;
    {
        const float4* w1v = (const float4*)w1;
        for (int k = 0; k < 128; ++k) {
            float4 wv = w1v[k * 32 + ec];
#pragma unroll
            for (int rr = 0; rr < 8; ++rr) {
                float xv = xln[(rg * 8 + rr) * 129 + k];
                acc[rr][0] += xv * wv.x; acc[rr][1] += xv * wv.y;
                acc[rr][2] += xv * wv.z; acc[rr][3] += xv * wv.w;
            }
        }
    }
    float4 b1v = ((const float4*)b1)[ec];
#pragma unroll
    for (int rr = 0; rr < 8; ++rr) {
        acc[rr][0] = gelu_exact(acc[rr][0] + b1v.x);
        acc[rr][1] = gelu_exact(acc[rr][1] + b1v.y);
        acc[rr][2] = gelu_exact(acc[rr][2] + b1v.z);
        acc[rr][3] = gelu_exact(acc[rr][3] + b1v.w);
    }
    __syncthreads();
#pragma unroll
    for (int rr = 0; rr < 8; ++rr)
#pragma unroll
        for (int j = 0; j < 4; ++j)
            xln[(rg * 8 + rr) * 129 + 4 * ec + j] = acc[rr][j];
    __syncthreads();
#pragma unroll
    for (int rr = 0; rr < 8; ++rr)
#pragma unroll
        for (int j = 0; j < 4; ++j) acc[rr][j] = 0.0f;
    {
        const float4* w2v = (const float4*)w2;
        for (int k = 0; k < 128; ++k) {
            float4 wv = w2v[k * 32 + ec];
#pragma unroll
            for (int rr = 0; rr < 8; ++rr) {
                float gv = xln[(rg * 8 + rr) * 129 + k];
                acc[rr][0] += gv * wv.x; acc[rr][1] += gv * wv.y;
                acc[rr][2] += gv * wv.z; acc[rr][3] += gv * wv.w;
            }
        }
    }
    float4 b2v = ((const float4*)b2)[ec];
#pragma unroll
    for (int rr = 0; rr < 8; ++rr) {
        acc[rr][0] += b2v.x + res[rr][0];
        acc[rr][1] += b2v.y + res[rr][1];
        acc[rr][2] += b2v.z + res[rr][2];
        acc[rr][3] += b2v.w + res[rr][3];
    }
    __syncthreads();
#pragma unroll
    for (int rr = 0; rr < 8; ++rr)
#pragma unroll
        for (int j = 0; j < 4; ++j)
            xln[(rg * 8 + rr) * 129 + 4 * ec + j] = acc[rr][j];
    __syncthreads();
    for (int r = wave; r < 64; r += 4) {
        float v0 = xln[r * 129 + lane];
        float v1 = xln[r * 129 + 64 + lane];
        float s = v0 + v1, ss = v0 * v0 + v1 * v1;
        for (int off = 32; off > 0; off >>= 1) {
            s += __shfl_xor(s, off);
            ss += __shfl_xor(ss, off);
        }
        float mean = s * (1.0f / 128.0f);
        float var = ss * (1.0f / 128.0f) - mean * mean;
        float rstd = rsqrtf(var + 1e-5f);
        size_t orow = FUSED ? ((size_t)b * TLEN + t0 + r) * DD : (R0 + r) * DD;
        out[orow + lane] = (v0 - mean) * rstd * ln2g[lane] + ln2b[lane];
        out[orow + 64 + lane] = (v1 - mean) * rstd * ln2g[64 + lane] + ln2b[64 + lane];
    }
}

extern "C" void kernel_launch(void* const* d_in, const int* in_sizes, int n_in,
                              void* d_out, int out_size, void* d_ws, size_t ws_size,
                              hipStream_t stream) {
    (void)in_sizes; (void)n_in; (void)out_size; (void)ws_size;
    const float* ecg   = (const float*)d_in[0];
    const float* image = (const float*)d_in[1];
    const float* tfb   = (const float*)d_in[2];
    const float* ifb   = (const float*)d_in[3];
    const float* sel   = (const float*)d_in[4];
    const float* i2t_w = (const float*)d_in[5];
    const float* i2t_b = (const float*)d_in[6];
    const float* t_ln1_g = (const float*)d_in[7];
    const float* t_ln1_b = (const float*)d_in[8];
    const float* t_w1 = (const float*)d_in[9];
    const float* t_b1 = (const float*)d_in[10];
    const float* t_w2 = (const float*)d_in[11];
    const float* t_b2 = (const float*)d_in[12];
    const float* t_ln2_g = (const float*)d_in[13];
    const float* t_ln2_b = (const float*)d_in[14];
    const float* i_ln1_g = (const float*)d_in[15];
    const float* i_ln1_b = (const float*)d_in[16];
    const float* i_w1 = (const float*)d_in[17];
    const float* i_b1 = (const float*)d_in[18];
    const float* i_w2 = (const float*)d_in[19];
    const float* i_b2 = (const float*)d_in[20];
    const float* i_ln2_g = (const float*)d_in[21];
    const float* i_ln2_b = (const float*)d_in[22];
    float* out = (float*)d_out;
    float* ws = (float*)d_ws;

    zero_kernel<<<16, 256, 0, stream>>>(ws + GBUF_OFF, BB * DD);
    prep_fb<<<(STOT * DD + 255) / 256, 256, 0, stream>>>(tfb, ws + FBT2_OFF);
    {
        dim3 tb(32, 8);
        dim3 tg(TLEN / 32, DD / 32, BB);
        transpose_btd<<<tg, tb, 0, stream>>>(ecg, ws + XT_OFF);
    }
    img_dft<<<BB * 11, 128, 0, stream>>>(image, ifb, sel, ws + ZI_OFF, ws + GBUF_OFF);
    gate_kernel<<<BB, 128, 0, stream>>>(ws + GBUF_OFF, i2t_w, i2t_b, ws + GATE_OFF);
    stft_filter_istft<<<BB * DD, 256, 0, stream>>>(ws + XT_OFF, ws + FBT2_OFF, ws + GATE_OFF);
    addnorm_kernel<1><<<BB * (TLEN / 64), 256, 0, stream>>>(
        ws + XT_OFF, ecg, t_ln1_g, t_ln1_b, t_w1, t_b1, t_w2, t_b2, t_ln2_g, t_ln2_b, out);
    img_irfft<<<BB * 14, 128, 0, stream>>>(ws + ZI_OFF, image, ws + X0I_OFF);
    addnorm_kernel<0><<<(BB * NPATCH) / 64, 256, 0, stream>>>(
        ws + X0I_OFF, nullptr, i_ln1_g, i_ln1_b, i_w1, i_b1, i_w2, i_b2, i_ln2_g, i_ln2_b,
        out + (size_t)BB * TLEN * DD);
}

// Round 5
// 727.981 us; speedup vs baseline: 1.3038x; 1.0992x over previous
//
#include <hip/hip_runtime.h>
#include <math.h>

#define BB 32
#define DD 128
#define TLEN 4096
#define NSEG 512
#define HOP 256
#define NFR 17
#define NBINS 257
#define STOT 4369
#define NPATCH 196
#define NFREQ 99
#define OLAL 4608

// workspace layout (float offsets)
#define FBT2_OFF 0
#define FBT2_SZ  (DD * NFR * NBINS * 2)       // 1,118,464
#define GBUF_OFF (FBT2_OFF + FBT2_SZ)
#define GATE_OFF (GBUF_OFF + BB * DD)
#define ZI_OFF   (GATE_OFF + BB * DD)
#define ZI_SZ    (BB * NFREQ * DD * 2)        // 811,008
#define X0I_OFF  (ZI_OFF + ZI_SZ)
#define X0I_SZ   (BB * NPATCH * DD)           // 802,816
#define XT_OFF   (X0I_OFF + X0I_SZ)

__device__ __forceinline__ float gelu_exact(float x) {
    return 0.5f * x * (1.0f + erff(x * 0.70710678118654752f));
}

// ---------------------------------------------------------------- zero gbuf
__global__ __launch_bounds__(256) void zero_kernel(float* p, int n) {
    int i = blockIdx.x * 256 + threadIdx.x;
    if (i < n) p[i] = 0.0f;
}

// ------------------------------------------------- tfb -> fbt2 (D,17,257,2)
// c coefficients: cos(fl(pi)) = cos(fl(3*pi)) = -1.0f exactly in fp32.
__global__ __launch_bounds__(256) void prep_fb(const float* __restrict__ tfb,
                                               float* __restrict__ fbt2) {
    int idx = blockIdx.x * 256 + threadIdx.x;
    if (idx >= STOT * DD) return;
    int d = idx & 127;
    int s = idx >> 7;
    float2 a = ((const float2*)tfb)[s * DD + d];
    float2 b = ((const float2*)tfb)[STOT * DD + s * DD + d];
    int f = s / NFR, t = s % NFR;
    float2 r;
    r.x = -(a.x + b.x);
    r.y = -(a.y + b.y);
    ((float2*)fbt2)[((size_t)d * NFR + t) * NBINS + f] = r;
}

// ------------------------------------------------- ecg (B,T,D) -> (B,D,T)
__global__ __launch_bounds__(256) void transpose_btd(const float* __restrict__ in,
                                                     float* __restrict__ out) {
    __shared__ float tile[32][33];
    int b = blockIdx.z;
    int t0 = blockIdx.x * 32;
    int d0 = blockIdx.y * 32;
    int lx = threadIdx.x;   // 0..31
    int ly = threadIdx.y;   // 0..7
    for (int i = ly; i < 32; i += 8)
        tile[i][lx] = in[((size_t)b * TLEN + t0 + i) * DD + d0 + lx];
    __syncthreads();
    for (int i = ly; i < 32; i += 8)
        out[((size_t)b * DD + d0 + i) * TLEN + t0 + lx] = tile[lx][i];
}

// ---------------------------------------- image rfft(ortho) + filter + g acc
__global__ __launch_bounds__(128) void img_dft(const float* __restrict__ image,
                                               const float* __restrict__ ifb,
                                               const float* __restrict__ sel,
                                               float* __restrict__ zi,
                                               float* __restrict__ gbuf) {
    __shared__ float ctab[NPATCH], stab[NPATCH];
    int b = blockIdx.x / 11;
    int fg = blockIdx.x % 11;
    int d = threadIdx.x;
    for (int m = d; m < NPATCH; m += 128) {
        ctab[m] = cospif(m * (2.0f / 196.0f));
        stab[m] = sinpif(m * (2.0f / 196.0f));
    }
    __syncthreads();
    float accr[9], acci[9];
    int mc[9];
#pragma unroll
    for (int j = 0; j < 9; ++j) { accr[j] = 0.0f; acci[j] = 0.0f; mc[j] = 0; }
    const float* img = image + (size_t)b * NPATCH * DD + d;
    for (int n = 0; n < NPATCH; ++n) {
        float v = img[(size_t)n * DD];
#pragma unroll
        for (int j = 0; j < 9; ++j) {
            float c = ctab[mc[j]], s = stab[mc[j]];
            accr[j] += v * c;
            acci[j] -= v * s;
            mc[j] += fg * 9 + j;
            if (mc[j] >= NPATCH) mc[j] -= NPATCH;
        }
    }
    float gg = 0.0f;
#pragma unroll
    for (int j = 0; j < 9; ++j) {
        int f = fg * 9 + j;
        float Xr = accr[j] * (1.0f / 14.0f);
        float Xi = acci[j] * (1.0f / 14.0f);
        float sr = (Xr * Xr - Xi * Xi) * (1.0f / 99.0f);
        float si = 2.0f * Xr * Xi * (1.0f / 99.0f);
        float2 f0 = ((const float2*)ifb)[f * DD + d];
        float2 f1 = ((const float2*)ifb)[NFREQ * DD + f * DD + d];
        float fbr = -(f0.x + f1.x), fbi = -(f0.y + f1.y);
        float zr = sr * fbr - si * fbi;
        float zm = sr * fbi + si * fbr;
        float2 o; o.x = zr; o.y = zm;
        ((float2*)zi)[((size_t)b * NFREQ + f) * DD + d] = o;
        float2 sl = ((const float2*)sel)[f * DD + d];
        gg += zr * sl.x - zm * sl.y;
    }
    atomicAdd(gbuf + b * DD + d, gg * (1.0f / 99.0f));
}

// ----------------------------------------------------- gate = g @ w^T + b
__global__ __launch_bounds__(128) void gate_kernel(const float* __restrict__ gbuf,
                                                   const float* __restrict__ w,
                                                   const float* __restrict__ bias,
                                                   float* __restrict__ gate) {
    __shared__ float gs[DD];
    int b = blockIdx.x, e = threadIdx.x;
    gs[e] = gbuf[b * DD + e];
    __syncthreads();
    float acc = bias[e];
    const float* wr = w + (size_t)e * DD;
    for (int d = 0; d < DD; ++d) acc += gs[d] * wr[d];
    gate[b * DD + e] = acc;
}

// ------------------------- per-(b,d): STFT -> filter*gate -> ISTFT, in-place
#define SKN 264   // skewed per-frame stride = SK(256)
#define SK(i) ((i) + ((i) >> 5))

__global__ __launch_bounds__(256, 4) void stft_filter_istft(
    float* xT, const float* __restrict__ fbt2, const float* __restrict__ gate) {
    __shared__ float ar[NFR * SKN];   // 4488
    __shared__ float ai[NFR * SKN];
    __shared__ float win[NSEG];
    __shared__ float twc[128], tws[128];
    int tid = threadIdx.x;
    int bd = blockIdx.x;              // b*128 + d
    int d = bd & 127;
    float gat = gate[bd];
    const float scl = gat * (1.0f / 4369.0f);
    float* xrow = xT + (size_t)bd * TLEN;
    const float2* fbrow = (const float2*)(fbt2 + (size_t)d * NFR * NBINS * 2);

    for (int j = tid; j < NSEG; j += 256)
        win[j] = 0.5f - 0.5f * cospif(j * (1.0f / 256.0f));   // sin^2(pi j/512)
    if (tid < 128) {
        twc[tid] = cospif(tid * (1.0f / 128.0f));             // e^{-2pi i j/256}
        tws[tid] = -sinpif(tid * (1.0f / 128.0f));
    }
    __syncthreads();

    for (int t = 0; t < NFR; ++t) {
        int m = tid;                       // 0..255
        int src = t * HOP + 2 * m - HOP;
        float e = 0.0f, o = 0.0f;
        if (src >= 0 && src < TLEN) {
            float2 v = *(const float2*)(xrow + src);
            e = v.x; o = v.y;
        }
        e *= win[2 * m]; o *= win[2 * m + 1];
        int r = __brev((unsigned)m) >> 24;
        ar[t * SKN + SK(r)] = e;
        ai[t * SKN + SK(r)] = o;
    }

    for (int s = 1; s <= 8; ++s) {
        __syncthreads();
        int half = 1 << (s - 1);
        for (int j = tid; j < NFR * 128; j += 256) {
            int t = j >> 7, m = j & 127;
            int base = t * SKN;
            int k = m & (half - 1);
            int p = ((m >> (s - 1)) << s) + k;
            int twi = k << (8 - s);
            float c = twc[twi], sn = tws[twi];
            int a0 = base + SK(p), a1 = base + SK(p + half);
            float ur = ar[a0], ui = ai[a0];
            float vr = ar[a1], vi = ai[a1];
            float tr = vr * c - vi * sn;
            float ti = vr * sn + vi * c;
            ar[a0] = ur + tr; ai[a0] = ui + ti;
            ar[a1] = ur - tr; ai[a1] = ui - ti;
        }
    }
    __syncthreads();

    float y1r[9], y1i[9], y2r[9], y2i[9];
#pragma unroll
    for (int it = 0; it < 9; ++it) {
        int j = tid + it * 256;
        if (j < NFR * 129) {
            int t = j / 129, m = j - t * 129;
            int base = t * SKN;
            const float2* fbr = fbrow + t * NBINS;
            if (m == 0) {
                float re = ar[base + SK(0)], im = ai[base + SK(0)];
                float z0 = (re + im) * (1.0f / 256.0f);
                float zN = (re - im) * (1.0f / 256.0f);
                float2 fb0 = fbr[0], fbN = fbr[256];
                y1r[it] = z0 * z0 * fb0.x * scl; y1i[it] = 0.0f;
                y2r[it] = zN * zN * fbN.x * scl; y2i[it] = 0.0f;
            } else if (m == 128) {
                float Zr = ar[base + SK(128)], Zi = ai[base + SK(128)];
                float zr = Zr * (1.0f / 256.0f), zi2 = -Zi * (1.0f / 256.0f);
                float sr = zr * zr - zi2 * zi2, si = 2.0f * zr * zi2;
                float2 fb = fbr[128];
                y1r[it] = (sr * fb.x - si * fb.y) * scl;
                y1i[it] = (sr * fb.y + si * fb.x) * scl;
                y2r[it] = 0.0f; y2i[it] = 0.0f;
            } else {
                float Amr = ar[base + SK(m)],       Ami = ai[base + SK(m)];
                float Acr = ar[base + SK(256 - m)], Aci = ai[base + SK(256 - m)];
                float c = cospif(m * (1.0f / 256.0f));
                float sn = sinpif(m * (1.0f / 256.0f));
                {
                    float Br = Acr, Bi = -Aci;
                    float xer = 0.5f * (Amr + Br), xei = 0.5f * (Ami + Bi);
                    float xo_r = 0.5f * (Ami - Bi), xo_i = -0.5f * (Amr - Br);
                    float Xr = xer + c * xo_r + sn * xo_i;
                    float Xi = xei + c * xo_i - sn * xo_r;
                    float zr = Xr * (1.0f / 256.0f), zi2 = Xi * (1.0f / 256.0f);
                    float sr = zr * zr - zi2 * zi2, si = 2.0f * zr * zi2;
                    float2 fb = fbr[m];
                    y1r[it] = (sr * fb.x - si * fb.y) * scl;
                    y1i[it] = (sr * fb.y + si * fb.x) * scl;
                }
                {
                    float Br = Amr, Bi = -Ami;
                    float xer = 0.5f * (Acr + Br), xei = 0.5f * (Aci + Bi);
                    float xo_r = 0.5f * (Aci - Bi), xo_i = -0.5f * (Acr - Br);
                    float Xr = xer - c * xo_r + sn * xo_i;
                    float Xi = xei - c * xo_i - sn * xo_r;
                    float zr = Xr * (1.0f / 256.0f), zi2 = Xi * (1.0f / 256.0f);
                    float sr = zr * zr - zi2 * zi2, si = 2.0f * zr * zi2;
                    float2 fb = fbr[256 - m];
                    y2r[it] = (sr * fb.x - si * fb.y) * scl;
                    y2i[it] = (sr * fb.y + si * fb.x) * scl;
                }
            }
        }
    }
    __syncthreads();

#pragma unroll
    for (int it = 0; it < 9; ++it) {
        int j = tid + it * 256;
        if (j < NFR * 129) {
            int t = j / 129, m = j - t * 129;
            int base = t * SKN;
            if (m == 0) {
                float Er = 0.5f * (y1r[it] + y2r[it]);
                float Dr = 0.5f * (y1r[it] - y2r[it]);
                ar[base + SK(0)] = Er;
                ai[base + SK(0)] = -Dr;
            } else if (m == 128) {
                ar[base + SK(1)] = y1r[it];
                ai[base + SK(1)] = y1i[it];
            } else {
                float c = cospif(m * (1.0f / 256.0f));
                float sn = sinpif(m * (1.0f / 256.0f));
                float Er = 0.5f * (y1r[it] + y2r[it]);
                float Ei = 0.5f * (y1i[it] - y2i[it]);
                float Dr = 0.5f * (y1r[it] - y2r[it]);
                float Di = 0.5f * (y1i[it] + y2i[it]);
                float Or = Dr * c - Di * sn;
                float Oi = Dr * sn + Di * c;
                int r1 = __brev((unsigned)m) >> 24;
                ar[base + SK(r1)] = Er - Oi;
                ai[base + SK(r1)] = -(Ei + Or);
                int r2 = __brev((unsigned)(256 - m)) >> 24;
                ar[base + SK(r2)] = Er + Oi;
                ai[base + SK(r2)] = Ei - Or;
            }
        }
    }

    for (int s = 1; s <= 8; ++s) {
        __syncthreads();
        int half = 1 << (s - 1);
        for (int j = tid; j < NFR * 128; j += 256) {
            int t = j >> 7, m = j & 127;
            int base = t * SKN;
            int k = m & (half - 1);
            int p = ((m >> (s - 1)) << s) + k;
            int twi = k << (8 - s);
            float c = twc[twi], sn = tws[twi];
            int a0 = base + SK(p), a1 = base + SK(p + half);
            float ur = ar[a0], ui = ai[a0];
            float vr = ar[a1], vi = ai[a1];
            float tr = vr * c - vi * sn;
            float ti = vr * sn + vi * c;
            ar[a0] = ur + tr; ai[a0] = ui + ti;
            ar[a1] = ur - tr; ai[a1] = ui - ti;
        }
    }
    __syncthreads();

    for (int j = tid; j < TLEN; j += 256) {
        int p = j + HOP;
        int t1 = p >> 8;
        int t0 = t1 - 1;
        int i1 = p & 255;
        int i0 = i1 + 256;
        int h1 = t1 * SKN + SK(i1 >> 1);
        int h0 = t0 * SKN + SK(i0 >> 1);
        float v1, v0;
        if (j & 1) { v1 = -ai[h1]; v0 = -ai[h0]; }
        else       { v1 =  ar[h1]; v0 =  ar[h0]; }
        float s = v0 * win[i0] + v1 * win[i1];
        float s2 = win[i1];
        float c2 = 1.0f - s2;
        xrow[j] = s / (s2 * s2 + c2 * c2);
    }
}

// ------------------------------------------- image irfft(ortho) + add image
__global__ __launch_bounds__(128) void img_irfft(const float* __restrict__ zi,
                                                 const float* __restrict__ image,
                                                 float* __restrict__ x0img) {
    __shared__ float ctab[NPATCH], stab[NPATCH];
    int b = blockIdx.x / 14;
    int ng = blockIdx.x % 14;
    int d = threadIdx.x;
    for (int m = d; m < NPATCH; m += 128) {
        ctab[m] = cospif(m * (2.0f / 196.0f));
        stab[m] = sinpif(m * (2.0f / 196.0f));
    }
    __syncthreads();
    const float2* zrow = (const float2*)zi + (size_t)b * NFREQ * DD + d;
    float acc[14];
    int mc[14];
    float2 z0 = zrow[0];
#pragma unroll
    for (int j = 0; j < 14; ++j) { acc[j] = z0.x; mc[j] = 0; }
    for (int f = 1; f <= 97; ++f) {
        float2 z = zrow[(size_t)f * DD];
#pragma unroll
        for (int j = 0; j < 14; ++j) {
            int n = ng * 14 + j;
            mc[j] += n;
            if (mc[j] >= NPATCH) mc[j] -= NPATCH;
            acc[j] += 2.0f * (z.x * ctab[mc[j]] - z.y * stab[mc[j]]);
        }
    }
    float2 z98 = zrow[98 * (size_t)DD];
#pragma unroll
    for (int j = 0; j < 14; ++j) {
        int n = ng * 14 + j;
        float a = acc[j] + ((n & 1) ? -z98.x : z98.x);
        float y = a * (1.0f / 14.0f);
        size_t idx = ((size_t)b * NPATCH + n) * DD + d;
        x0img[idx] = y + image[idx];
    }
}

// ------------------------------- addnorm: LN1 -> gelu MLP (fp32) -> LN2
// Round-2 structure (known-good). Changes: stride 129->132 (16B-aligned
// rows), K processed in chunks of 4 with ds_read_b128 x-broadcasts
// (8 LDS insts per 128 FMA instead of 32), float4 LDS writes for g/h.
#define XLNS 132

template <int FUSED>
__global__ __launch_bounds__(256) void addnorm_kernel(
    const float* __restrict__ srcA, const float* __restrict__ srcB,
    const float* __restrict__ ln1g, const float* __restrict__ ln1b,
    const float* __restrict__ w1, const float* __restrict__ b1,
    const float* __restrict__ w2, const float* __restrict__ b2,
    const float* __restrict__ ln2g, const float* __restrict__ ln2b,
    float* __restrict__ out) {
    __shared__ __align__(16) float xln[64 * XLNS];   // reused: x -> g -> h
    int tid = threadIdx.x;
    int b = 0, t0 = 0;
    size_t R0 = 0;
    // ---- Phase A: build x0
    if (FUSED) {
        b = blockIdx.x >> 6;
        t0 = (blockIdx.x & 63) * 64;
        for (int i = tid; i < 64 * 128; i += 256) {
            int dd = i >> 6, r = i & 63;
            xln[r * XLNS + dd] = srcA[((size_t)b * DD + dd) * TLEN + t0 + r];
        }
        __syncthreads();
        for (int i = tid; i < 64 * 128; i += 256) {
            int r = i >> 7, dd = i & 127;
            xln[r * XLNS + dd] += srcB[((size_t)b * TLEN + t0 + r) * DD + dd];
        }
    } else {
        R0 = (size_t)blockIdx.x * 64;
        for (int i = tid; i < 64 * 128; i += 256) {
            int r = i >> 7, dd = i & 127;
            xln[r * XLNS + dd] = srcA[(R0 + r) * DD + dd];
        }
    }
    __syncthreads();
    // ---- LN1 (wave per row)
    int wave = tid >> 6, lane = tid & 63;
    for (int r = wave; r < 64; r += 4) {
        float v0 = xln[r * XLNS + lane];
        float v1 = xln[r * XLNS + 64 + lane];
        float s = v0 + v1, ss = v0 * v0 + v1 * v1;
        for (int off = 32; off > 0; off >>= 1) {
            s += __shfl_xor(s, off);
            ss += __shfl_xor(ss, off);
        }
        float mean = s * (1.0f / 128.0f);
        float var = ss * (1.0f / 128.0f) - mean * mean;
        float rstd = rsqrtf(var + 1e-5f);
        xln[r * XLNS + lane] = (v0 - mean) * rstd * ln1g[lane] + ln1b[lane];
        xln[r * XLNS + 64 + lane] = (v1 - mean) * rstd * ln1g[64 + lane] + ln1b[64 + lane];
    }
    __syncthreads();
    // ---- thread tiling: 8 rows x 4 cols each
    int ec = tid & 31, rg = tid >> 5;
    float res[8][4];
#pragma unroll
    for (int rr = 0; rr < 8; ++rr) {
        float4 rv = *(const float4*)&xln[(rg * 8 + rr) * XLNS + 4 * ec];
        res[rr][0] = rv.x; res[rr][1] = rv.y; res[rr][2] = rv.z; res[rr][3] = rv.w;
    }
    // ---- Phase B: g = gelu(x @ w1 + b1)
    float acc[8][4];
#pragma unroll
    for (int rr = 0; rr < 8; ++rr)
#pragma unroll
        for (int j = 0; j < 4; ++j) acc[rr][j] = 0.0f;
    {
        const float4* w1v = (const float4*)w1;
        for (int k = 0; k < 128; k += 4) {
            float4 wa = w1v[(k + 0) * 32 + ec];
            float4 wb = w1v[(k + 1) * 32 + ec];
            float4 wc = w1v[(k + 2) * 32 + ec];
            float4 wd = w1v[(k + 3) * 32 + ec];
#pragma unroll
            for (int rr = 0; rr < 8; ++rr) {
                float4 xv = *(const float4*)&xln[(rg * 8 + rr) * XLNS + k];
                acc[rr][0] += xv.x * wa.x + xv.y * wb.x + xv.z * wc.x + xv.w * wd.x;
                acc[rr][1] += xv.x * wa.y + xv.y * wb.y + xv.z * wc.y + xv.w * wd.y;
                acc[rr][2] += xv.x * wa.z + xv.y * wb.z + xv.z * wc.z + xv.w * wd.z;
                acc[rr][3] += xv.x * wa.w + xv.y * wb.w + xv.z * wc.w + xv.w * wd.w;
            }
        }
    }
    float4 b1v = ((const float4*)b1)[ec];
#pragma unroll
    for (int rr = 0; rr < 8; ++rr) {
        acc[rr][0] = gelu_exact(acc[rr][0] + b1v.x);
        acc[rr][1] = gelu_exact(acc[rr][1] + b1v.y);
        acc[rr][2] = gelu_exact(acc[rr][2] + b1v.z);
        acc[rr][3] = gelu_exact(acc[rr][3] + b1v.w);
    }
    __syncthreads();   // all reads of xln(=x) done
#pragma unroll
    for (int rr = 0; rr < 8; ++rr) {
        float4 gv; gv.x = acc[rr][0]; gv.y = acc[rr][1]; gv.z = acc[rr][2]; gv.w = acc[rr][3];
        *(float4*)&xln[(rg * 8 + rr) * XLNS + 4 * ec] = gv;   // xln := g
    }
    __syncthreads();
    // ---- Phase C: h = g @ w2 + b2 + res
#pragma unroll
    for (int rr = 0; rr < 8; ++rr)
#pragma unroll
        for (int j = 0; j < 4; ++j) acc[rr][j] = 0.0f;
    {
        const float4* w2v = (const float4*)w2;
        for (int k = 0; k < 128; k += 4) {
            float4 wa = w2v[(k + 0) * 32 + ec];
            float4 wb = w2v[(k + 1) * 32 + ec];
            float4 wc = w2v[(k + 2) * 32 + ec];
            float4 wd = w2v[(k + 3) * 32 + ec];
#pragma unroll
            for (int rr = 0; rr < 8; ++rr) {
                float4 xv = *(const float4*)&xln[(rg * 8 + rr) * XLNS + k];
                acc[rr][0] += xv.x * wa.x + xv.y * wb.x + xv.z * wc.x + xv.w * wd.x;
                acc[rr][1] += xv.x * wa.y + xv.y * wb.y + xv.z * wc.y + xv.w * wd.y;
                acc[rr][2] += xv.x * wa.z + xv.y * wb.z + xv.z * wc.z + xv.w * wd.z;
                acc[rr][3] += xv.x * wa.w + xv.y * wb.w + xv.z * wc.w + xv.w * wd.w;
            }
        }
    }
    float4 b2v = ((const float4*)b2)[ec];
#pragma unroll
    for (int rr = 0; rr < 8; ++rr) {
        acc[rr][0] += b2v.x + res[rr][0];
        acc[rr][1] += b2v.y + res[rr][1];
        acc[rr][2] += b2v.z + res[rr][2];
        acc[rr][3] += b2v.w + res[rr][3];
    }
    __syncthreads();   // all reads of xln(=g) done
#pragma unroll
    for (int rr = 0; rr < 8; ++rr) {
        float4 hv; hv.x = acc[rr][0]; hv.y = acc[rr][1]; hv.z = acc[rr][2]; hv.w = acc[rr][3];
        *(float4*)&xln[(rg * 8 + rr) * XLNS + 4 * ec] = hv;   // xln := h
    }
    __syncthreads();
    // ---- LN2 + store
    for (int r = wave; r < 64; r += 4) {
        float v0 = xln[r * XLNS + lane];
        float v1 = xln[r * XLNS + 64 + lane];
        float s = v0 + v1, ss = v0 * v0 + v1 * v1;
        for (int off = 32; off > 0; off >>= 1) {
            s += __shfl_xor(s, off);
            ss += __shfl_xor(ss, off);
        }
        float mean = s * (1.0f / 128.0f);
        float var = ss * (1.0f / 128.0f) - mean * mean;
        float rstd = rsqrtf(var + 1e-5f);
        size_t orow = FUSED ? ((size_t)b * TLEN + t0 + r) * DD : (R0 + r) * DD;
        out[orow + lane] = (v0 - mean) * rstd * ln2g[lane] + ln2b[lane];
        out[orow + 64 + lane] = (v1 - mean) * rstd * ln2g[64 + lane] + ln2b[64 + lane];
    }
}

extern "C" void kernel_launch(void* const* d_in, const int* in_sizes, int n_in,
                              void* d_out, int out_size, void* d_ws, size_t ws_size,
                              hipStream_t stream) {
    (void)in_sizes; (void)n_in; (void)out_size; (void)ws_size;
    const float* ecg   = (const float*)d_in[0];
    const float* image = (const float*)d_in[1];
    const float* tfb   = (const float*)d_in[2];
    const float* ifb   = (const float*)d_in[3];
    const float* sel   = (const float*)d_in[4];
    const float* i2t_w = (const float*)d_in[5];
    const float* i2t_b = (const float*)d_in[6];
    const float* t_ln1_g = (const float*)d_in[7];
    const float* t_ln1_b = (const float*)d_in[8];
    const float* t_w1 = (const float*)d_in[9];
    const float* t_b1 = (const float*)d_in[10];
    const float* t_w2 = (const float*)d_in[11];
    const float* t_b2 = (const float*)d_in[12];
    const float* t_ln2_g = (const float*)d_in[13];
    const float* t_ln2_b = (const float*)d_in[14];
    const float* i_ln1_g = (const float*)d_in[15];
    const float* i_ln1_b = (const float*)d_in[16];
    const float* i_w1 = (const float*)d_in[17];
    const float* i_b1 = (const float*)d_in[18];
    const float* i_w2 = (const float*)d_in[19];
    const float* i_b2 = (const float*)d_in[20];
    const float* i_ln2_g = (const float*)d_in[21];
    const float* i_ln2_b = (const float*)d_in[22];
    float* out = (float*)d_out;
    float* ws = (float*)d_ws;

    zero_kernel<<<16, 256, 0, stream>>>(ws + GBUF_OFF, BB * DD);
    prep_fb<<<(STOT * DD + 255) / 256, 256, 0, stream>>>(tfb, ws + FBT2_OFF);
    {
        dim3 tb(32, 8);
        dim3 tg(TLEN / 32, DD / 32, BB);
        transpose_btd<<<tg, tb, 0, stream>>>(ecg, ws + XT_OFF);
    }
    img_dft<<<BB * 11, 128, 0, stream>>>(image, ifb, sel, ws + ZI_OFF, ws + GBUF_OFF);
    gate_kernel<<<BB, 128, 0, stream>>>(ws + GBUF_OFF, i2t_w, i2t_b, ws + GATE_OFF);
    stft_filter_istft<<<BB * DD, 256, 0, stream>>>(ws + XT_OFF, ws + FBT2_OFF, ws + GATE_OFF);
    addnorm_kernel<1><<<BB * (TLEN / 64), 256, 0, stream>>>(
        ws + XT_OFF, ecg, t_ln1_g, t_ln1_b, t_w1, t_b1, t_w2, t_b2, t_ln2_g, t_ln2_b, out);
    img_irfft<<<BB * 14, 128, 0, stream>>>(ws + ZI_OFF, image, ws + X0I_OFF);
    addnorm_kernel<0><<<(BB * NPATCH) / 64, 256, 0, stream>>>(
        ws + X0I_OFF, nullptr, i_ln1_g, i_ln1_b, i_w1, i_b1, i_w2, i_b2, i_ln2_g, i_ln2_b,
        out + (size_t)BB * TLEN * DD);
}